// Round 15
// baseline (6127.795 us; speedup 1.0000x reference)
//
#include <hip/hip_runtime.h>
#include <hip/hip_bf16.h>

#define B_ 32
#define S_ 64
#define H_ 512
#define V_ 32000
#define T_ 64

typedef __bf16 bf16x8 __attribute__((ext_vector_type(8)));
typedef float f32x4 __attribute__((ext_vector_type(4)));

__device__ __forceinline__ float fast_tanh(float x) {
  float e = __expf(2.0f * x);
  return 1.0f - 2.0f / (e + 1.0f);
}
__device__ __forceinline__ float fast_sigmoid(float x) {
  return 1.0f / (1.0f + __expf(-x));
}
__device__ __forceinline__ int ld_agent(const int* p) {
  return __hip_atomic_load(p, __ATOMIC_RELAXED, __HIP_MEMORY_SCOPE_AGENT);
}
__device__ __forceinline__ void st_agent_f(float* p, float v) {
  __hip_atomic_store(p, v, __ATOMIC_RELAXED, __HIP_MEMORY_SCOPE_AGENT);
}
__device__ __forceinline__ void st_agent_i(int* p, int v) {
  __hip_atomic_store(p, v, __ATOMIC_RELAXED, __HIP_MEMORY_SCOPE_AGENT);
}

// ---------------- merged prep kernel (block-ranged) ----------------
// [0,2048): emb gather->bf16 ; [2048,3072): enc cvt ; [3072,4608): wihc cvt ;
// [4608,6656): wq/whh cvt ; [6656,6787): init flags/rowsum.

__global__ __launch_bounds__(256) void k_prep(
    const int* __restrict__ tgt, const float* __restrict__ emb,
    const float* __restrict__ enc, const float* __restrict__ W_ih,
    const float* __restrict__ Wq, const float* __restrict__ W_hh,
    __hip_bfloat16* __restrict__ emb_bf, __hip_bfloat16* __restrict__ enc_bf,
    __hip_bfloat16* __restrict__ wihc_bf, __hip_bfloat16* __restrict__ wq_bf,
    __hip_bfloat16* __restrict__ whh_bf,
    int* __restrict__ flags, float* __restrict__ rowsum) {
  const int bid = blockIdx.x, tid = threadIdx.x;
  if (bid < 2048) {
    const int t = bid >> 5, b = bid & 31;
    const int tok = (t == 0) ? 0 : tgt[b * T_ + t - 1];
    const float* src = emb + (size_t)tok * H_;
    __hip_bfloat16* dst = emb_bf + (size_t)bid * H_;
    for (int jj = tid; jj < H_; jj += 256) dst[jj] = __float2bfloat16(src[jj]);
  } else if (bid < 3072) {
    const int i = (bid - 2048) * 256 + tid;          // < 262144 float4s
    const float4 v = ((const float4*)enc)[i];
    union { __hip_bfloat16 h[4]; uint2 u; } cv;
    cv.h[0] = __float2bfloat16(v.x); cv.h[1] = __float2bfloat16(v.y);
    cv.h[2] = __float2bfloat16(v.z); cv.h[3] = __float2bfloat16(v.w);
    *(uint2*)(enc_bf + (size_t)i * 4) = cv.u;
  } else if (bid < 4608) {
    if (tid < 128) {
      const int row = bid - 3072;                    // 0..1535
      const int c4 = tid * 4;
      const float4 v = *(const float4*)(W_ih + (size_t)row * 1024 + 512 + c4);
      union { __hip_bfloat16 h[4]; uint2 u; } cv;
      cv.h[0] = __float2bfloat16(v.x); cv.h[1] = __float2bfloat16(v.y);
      cv.h[2] = __float2bfloat16(v.z); cv.h[3] = __float2bfloat16(v.w);
      *(uint2*)(wihc_bf + (size_t)row * 512 + c4) = cv.u;
    }
  } else if (bid < 6656) {
    const int row = bid - 4608;                      // 0..2047
    const int c2 = tid * 2;
    const float* src = (row < 512) ? (Wq + (size_t)row * 512)
                                   : (W_hh + (size_t)(row - 512) * 512);
    __hip_bfloat16* dst = (row < 512) ? (wq_bf + (size_t)row * 512)
                                      : (whh_bf + (size_t)(row - 512) * 512);
    const float2 v = *(const float2*)(src + c2);
    union { __hip_bfloat16 h[2]; unsigned u; } cv;
    cv.h[0] = __float2bfloat16(v.x); cv.h[1] = __float2bfloat16(v.y);
    *(unsigned*)(dst + c2) = cv.u;
  } else {
    const int i = (bid - 6656) * 256 + tid;
    if (i < 512)
      __hip_atomic_store(&flags[i], 0, __ATOMIC_RELAXED, __HIP_MEMORY_SCOPE_AGENT);
    else if (i < 33280) rowsum[i - 512] = 0.f;
  }
}

// ---------------- bf16-MFMA GEMM: C[M,N] = A[M,K] @ B[N,K]^T (+bias) ----------------

template <bool BF16OUT>
__global__ __launch_bounds__(256) void k_gemm(
    const __hip_bfloat16* __restrict__ A, int lda,
    const float* __restrict__ B, int ldb,
    const float* __restrict__ bias,
    void* __restrict__ Cv, int ldc, int K) {
  __shared__ float pool[128 * 68];
  __hip_bfloat16* Asub = (__hip_bfloat16*)pool;
  __hip_bfloat16* Bsub = (__hip_bfloat16*)(pool + 2048);
  const int tid = threadIdx.x;
  const int lane = tid & 63, wave = tid >> 6;
  const int wr = wave >> 1, wc = wave & 1;
  const int n0 = blockIdx.x * 128, m0 = blockIdx.y * 128;
  f32x4 acc[4][4];
#pragma unroll
  for (int i = 0; i < 4; ++i)
#pragma unroll
    for (int jj = 0; jj < 4; ++jj) acc[i][jj] = (f32x4){0.f, 0.f, 0.f, 0.f};

  for (int k0 = 0; k0 < K; k0 += 32) {
    uint4 a_v[2];
#pragma unroll
    for (int rr = 0; rr < 2; ++rr) {
      const int seg = tid + rr * 256;
      const int row = seg >> 2, ks8 = (seg & 3) * 8;
      a_v[rr] = *(const uint4*)(A + (size_t)(m0 + row) * lda + k0 + ks8);
    }
    float4 b_v[4];
#pragma unroll
    for (int rr = 0; rr < 4; ++rr) {
      const int idx = tid + rr * 256;
      const int n = idx >> 3, kg = (idx & 7) * 4;
      b_v[rr] = *(const float4*)(B + (size_t)(n0 + n) * ldb + k0 + kg);
    }
    __syncthreads();
#pragma unroll
    for (int rr = 0; rr < 2; ++rr) {
      const int seg = tid + rr * 256;
      *(uint4*)(Asub + seg * 8) = a_v[rr];
    }
#pragma unroll
    for (int rr = 0; rr < 4; ++rr) {
      const int idx = tid + rr * 256;
      const int n = idx >> 3, kg = (idx & 7) * 4;
      union { __hip_bfloat16 h[4]; uint2 u; } cv;
      cv.h[0] = __float2bfloat16(b_v[rr].x);
      cv.h[1] = __float2bfloat16(b_v[rr].y);
      cv.h[2] = __float2bfloat16(b_v[rr].z);
      cv.h[3] = __float2bfloat16(b_v[rr].w);
      *(uint2*)(Bsub + n * 32 + kg) = cv.u;
    }
    __syncthreads();
    bf16x8 af[4], bfr[4];
#pragma unroll
    for (int mi = 0; mi < 4; ++mi)
      af[mi] = *(const bf16x8*)(Asub + (wr * 64 + mi * 16 + (lane & 15)) * 32 + (lane >> 4) * 8);
#pragma unroll
    for (int ni = 0; ni < 4; ++ni)
      bfr[ni] = *(const bf16x8*)(Bsub + (wc * 64 + ni * 16 + (lane & 15)) * 32 + (lane >> 4) * 8);
#pragma unroll
    for (int mi = 0; mi < 4; ++mi)
#pragma unroll
      for (int ni = 0; ni < 4; ++ni)
        acc[mi][ni] = __builtin_amdgcn_mfma_f32_16x16x32_bf16(af[mi], bfr[ni], acc[mi][ni], 0, 0, 0);
  }

  float* Cs = pool;
  const int r4 = (lane >> 4) * 4, cc = lane & 15;
#pragma unroll
  for (int hf = 0; hf < 2; ++hf) {
    __syncthreads();
    if (wc == hf) {
#pragma unroll
      for (int ni = 0; ni < 4; ++ni) {
        const float bb = bias ? bias[n0 + hf * 64 + ni * 16 + cc] : 0.f;
#pragma unroll
        for (int mi = 0; mi < 4; ++mi)
#pragma unroll
          for (int i = 0; i < 4; ++i)
            Cs[(wr * 64 + mi * 16 + r4 + i) * 68 + ni * 16 + cc] = acc[mi][ni][i] + bb;
      }
    }
    __syncthreads();
    const int rowp = tid >> 4, colg = tid & 15;
#pragma unroll
    for (int pass = 0; pass < 8; ++pass) {
      const int row = pass * 16 + rowp;
      const float4 v = *(const float4*)(Cs + row * 68 + colg * 4);
      if constexpr (BF16OUT) {
        union { __hip_bfloat16 h[4]; uint2 u; } cv;
        cv.h[0] = __float2bfloat16(v.x); cv.h[1] = __float2bfloat16(v.y);
        cv.h[2] = __float2bfloat16(v.z); cv.h[3] = __float2bfloat16(v.w);
        *(uint2*)((__hip_bfloat16*)Cv + (size_t)(m0 + row) * ldc + n0 + hf * 64 + colg * 4) = cv.u;
      } else {
        *(float4*)((float*)Cv + (size_t)(m0 + row) * ldc + n0 + hf * 64 + colg * 4) = v;
      }
    }
  }
}

// ---------------- recurrence: 32 same-XCD clusters x 8 blocks, ONE rendezvous/step ----------------
// Identical to the r14 kernel (passed correctness) EXCEPT the full-gic loop is
// a 2-deep register pipeline (uint4 e[2][8]) instead of a fully-unrolled 48-
// uint4 batch -> no VGPR spill. Protocol r12-verified: agent write-through
// payloads + vmcnt(0) + monotone 1-line flags + per-step rotating buffers.

__global__ __launch_bounds__(256) void k_recur(
    const __hip_bfloat16* __restrict__ wq_bf, const __hip_bfloat16* __restrict__ whh_bf,
    const float* __restrict__ bq,
    const __hip_bfloat16* __restrict__ kproj_bf,
    const float* __restrict__ Wv, const float* __restrict__ bv,
    const __hip_bfloat16* __restrict__ encT_bf, const float* __restrict__ giemb,
    const float* __restrict__ b_hh, const float* __restrict__ ehs,
    float* partial_st, float* gh_st, int* flags,
    float* __restrict__ attn_out, __hip_bfloat16* __restrict__ Hall,
    float* __restrict__ hfin) {
  const int tid = threadIdx.x;
  const int bid = blockIdx.x;
  const int b = 4 * (bid & 7) + ((bid >> 3) & 3);   // cluster (batch)
  const int j = bid >> 5;                           // slice

  const int rowg = tid >> 3, lane8 = tid & 7;
  const int s_idx = tid >> 2, q4 = tid & 3;
  f32x4 wvr[4];
#pragma unroll
  for (int i = 0; i < 4; ++i)
    wvr[i] = *(const f32x4*)(Wv + j * 64 + q4 * 16 + i * 4);
  float bq2[2];
#pragma unroll
  for (int i = 0; i < 2; ++i) bq2[i] = bq[j * 64 + i * 32 + rowg];
  const float bv0 = bv[0];

  __shared__ float h_s[8 * 68];        // padded: dim d -> (d>>6)*68 + (d&63)
  __shared__ float q_s[64];
  __shared__ float ps_s[512];
  __shared__ float ghall_s[1536];
  __shared__ float w_s[64];

  // h0 from encoder_hidden_state (identical in every cluster member)
  if (tid < 128) {
    const float4 v = *(const float4*)(ehs + b * H_ + tid * 4);
    const int g = (tid * 4) >> 6, off = (tid * 4) & 63;
    *(float4*)(h_s + g * 68 + off) = v;
  }
  __syncthreads();

  for (int t = 0; t < T_; ++t) {
    f32x4 hf4[16];
#pragma unroll
    for (int i = 0; i < 16; ++i)
      hf4[i] = *(const f32x4*)(h_s + lane8 * 68 + i * 4);

    auto dotw = [&](const __hip_bfloat16* wrow) -> float {
      const uint4* w8 = (const uint4*)wrow;
      float p = 0.f;
#pragma unroll
      for (int i = 0; i < 8; ++i) {
        const uint4 w = w8[lane8 * 8 + i];
        const f32x4 ha = hf4[2 * i], hb = hf4[2 * i + 1];
        p += __uint_as_float(w.x << 16) * ha[0] + __uint_as_float(w.x & 0xffff0000u) * ha[1];
        p += __uint_as_float(w.y << 16) * ha[2] + __uint_as_float(w.y & 0xffff0000u) * ha[3];
        p += __uint_as_float(w.z << 16) * hb[0] + __uint_as_float(w.z & 0xffff0000u) * hb[1];
        p += __uint_as_float(w.w << 16) * hb[2] + __uint_as_float(w.w & 0xffff0000u) * hb[3];
      }
      p += __shfl_xor(p, 1); p += __shfl_xor(p, 2); p += __shfl_xor(p, 4);
      return p;
    };

    // ---- q slice: rows j*64 .. +64 of Wq ----
#pragma unroll
    for (int i = 0; i < 2; ++i) {
      const float p = dotw(wq_bf + (size_t)(j * 64 + i * 32 + rowg) * 512);
      if (lane8 == 0) q_s[i * 32 + rowg] = p + bq2[i];
    }
    __syncthreads();

    // ---- partial scores over slice j's 64 dims (publish early) ----
    {
      const uint4* kp = (const uint4*)(kproj_bf + ((size_t)(b * S_ + s_idx)) * H_ + j * 64 + q4 * 16);
      const float4* qp = (const float4*)(q_s + q4 * 16);
      float sc = 0.f;
#pragma unroll
      for (int i = 0; i < 2; ++i) {
        const uint4 k = kp[i];
        const float4 qa = qp[2 * i], qb = qp[2 * i + 1];
        const f32x4 va = wvr[2 * i], vb = wvr[2 * i + 1];
        sc += va[0] * fast_tanh(qa.x + __uint_as_float(k.x << 16));
        sc += va[1] * fast_tanh(qa.y + __uint_as_float(k.x & 0xffff0000u));
        sc += va[2] * fast_tanh(qa.z + __uint_as_float(k.y << 16));
        sc += va[3] * fast_tanh(qa.w + __uint_as_float(k.y & 0xffff0000u));
        sc += vb[0] * fast_tanh(qb.x + __uint_as_float(k.z << 16));
        sc += vb[1] * fast_tanh(qb.y + __uint_as_float(k.z & 0xffff0000u));
        sc += vb[2] * fast_tanh(qb.z + __uint_as_float(k.w << 16));
        sc += vb[3] * fast_tanh(qb.w + __uint_as_float(k.w & 0xffff0000u));
      }
      sc += __shfl_xor(sc, 1); sc += __shfl_xor(sc, 2);
      if (q4 == 0)
        st_agent_f(&partial_st[((size_t)(t * B_ + b)) * 512 + j * 64 + s_idx], sc);
    }

    // ---- gh slice (192 rows) -> publish; overlaps partial flight ----
    {
      const size_t ghslot = ((size_t)(t * B_ + b) * 8 + j) * 192;
#pragma unroll
      for (int i = 0; i < 6; ++i) {
        const int row = (i >> 1) * 512 + j * 64 + (i & 1) * 32 + rowg;
        const float p = dotw(whh_bf + (size_t)row * 512);
        if (lane8 == 0) st_agent_f(&gh_st[ghslot + i * 32 + rowg], p);
      }
    }
    asm volatile("s_waitcnt vmcnt(0)" ::: "memory");
    __syncthreads();
    if (tid == 0)
      st_agent_i(&flags[b * 16 + j], t + 1);

    // ---- ONE rendezvous: wait all 8 slices ----
    if (tid < 8) {
      while (ld_agent(&flags[b * 16 + tid]) < t + 1) __builtin_amdgcn_s_sleep(1);
    }
    __syncthreads();
    asm volatile("" ::: "memory");

    // ---- read partials (512 f) + gh_all (1536 f) once, cold ----
    if (tid < 128) {
      *(float4*)(ps_s + tid * 4) =
          *(const float4*)(partial_st + (size_t)(t * B_ + b) * 512 + tid * 4);
      const float* gsrc = gh_st + (size_t)(t * B_ + b) * 1536;
#pragma unroll
      for (int k = 0; k < 3; ++k)
        *(float4*)(ghall_s + k * 512 + tid * 4) = *(const float4*)(gsrc + k * 512 + tid * 4);
    }
    __syncthreads();

    // ---- softmax (redundant, bitwise identical) ----
    if (tid < 64) {
      float sc = bv0;
#pragma unroll
      for (int jj = 0; jj < 8; ++jj) sc += ps_s[jj * 64 + tid];
      float m = sc;
#pragma unroll
      for (int d = 32; d > 0; d >>= 1) m = fmaxf(m, __shfl_xor(m, d));
      const float e = __expf(sc - m);
      float sum = e;
#pragma unroll
      for (int d = 32; d > 0; d >>= 1) sum += __shfl_xor(sum, d);
      const float w = e / sum;
      w_s[tid] = w;
      if (j == (b & 7)) attn_out[((size_t)b * T_ + t) * S_ + tid] = w;
    }
    __syncthreads();

    // ---- FULL gic: thread's 6 rows (row = k*256 + tid), 2-deep reg pipeline ----
    float gic_r[6];
    {
      const float4* wp4 = (const float4*)w_s;
      uint4 e[2][8];
      {
        const uint4* ep0 = (const uint4*)(encT_bf + (size_t)tid * 2048 + b * 64);
#pragma unroll
        for (int i = 0; i < 8; ++i) e[0][i] = ep0[i];
      }
#pragma unroll
      for (int k = 0; k < 6; ++k) {
        if (k < 5) {
          const uint4* epn = (const uint4*)(encT_bf + (size_t)((k + 1) * 256 + tid) * 2048 + b * 64);
#pragma unroll
          for (int i = 0; i < 8; ++i) e[(k + 1) & 1][i] = epn[i];
        }
        float a = 0.f;
#pragma unroll
        for (int i = 0; i < 8; ++i) {
          const uint4 e4 = e[k & 1][i];
          const float4 w0 = wp4[2 * i], w1 = wp4[2 * i + 1];
          a += __uint_as_float(e4.x << 16) * w0.x + __uint_as_float(e4.x & 0xffff0000u) * w0.y;
          a += __uint_as_float(e4.y << 16) * w0.z + __uint_as_float(e4.y & 0xffff0000u) * w0.w;
          a += __uint_as_float(e4.z << 16) * w1.x + __uint_as_float(e4.z & 0xffff0000u) * w1.y;
          a += __uint_as_float(e4.w << 16) * w1.z + __uint_as_float(e4.w & 0xffff0000u) * w1.w;
        }
        gic_r[k] = a;
      }
    }

    // ---- FULL gates (2 dims/thread), h_new -> LDS; single-writer Hall ----
    {
      const size_t grow = ((size_t)t * B_ + b) * 1536;
      const bool writer = (j == (b & 7));
#pragma unroll
      for (int half = 0; half < 2; ++half) {
        const int hh = tid + half * 256;
        const int jj = hh >> 6, dd = hh & 63;
        const float ir  = giemb[grow + hh]        + gic_r[half];
        const float iz  = giemb[grow + 512 + hh]  + gic_r[2 + half];
        const float in_ = giemb[grow + 1024 + hh] + gic_r[4 + half];
        const float hr  = ghall_s[jj * 192 + dd]        + b_hh[hh];
        const float hz  = ghall_s[jj * 192 + 64 + dd]   + b_hh[512 + hh];
        const float hn  = ghall_s[jj * 192 + 128 + dd]  + b_hh[1024 + hh];
        const float rg = fast_sigmoid(ir + hr);
        const float zg = fast_sigmoid(iz + hz);
        const float ng = fast_tanh(in_ + rg * hn);
        const float ho = h_s[jj * 68 + dd];
        const float hv = (1.f - zg) * ng + zg * ho;
        h_s[jj * 68 + dd] = hv;                  // own dim: no cross-thread hazard
        if (writer) {
          Hall[((size_t)b * T_ + t) * H_ + hh] = __float2bfloat16(hv);
          if (t == T_ - 1) hfin[b * H_ + hh] = hv;
        }
      }
    }
    __syncthreads();   // h_s ready for next step
  }
}

// ---------------- logits GEMM + fused sumexp (XCD-chunked n-tiles) ----------------
// |h|<=1 -> |logit| <~ 10 -> no-max sumexp fp32-safe. rowsum padded: 1 line/row.

__global__ __launch_bounds__(256) void k_logits(
    const __hip_bfloat16* __restrict__ Hall, const float* __restrict__ Wo,
    const float* __restrict__ bo, float* __restrict__ out0,
    float* __restrict__ rowsum) {
  __shared__ float pool[128 * 68];
  __hip_bfloat16* Asub = (__hip_bfloat16*)pool;
  __hip_bfloat16* Bsub = (__hip_bfloat16*)(pool + 2048);
  const int tid = threadIdx.x;
  const int lane = tid & 63, wave = tid >> 6;
  const int wr = wave >> 1, wc = wave & 1;
  const int flat = blockIdx.x;                  // 0..3999
  const int nf = (flat & 7) * 500 + (flat >> 3);
  const int m0 = (nf & 15) * 128, n0 = (nf >> 4) * 128;
  f32x4 acc[4][4];
#pragma unroll
  for (int i = 0; i < 4; ++i)
#pragma unroll
    for (int jj = 0; jj < 4; ++jj) acc[i][jj] = (f32x4){0.f, 0.f, 0.f, 0.f};

  for (int k0 = 0; k0 < 512; k0 += 32) {
    uint4 a_v[2];
#pragma unroll
    for (int rr = 0; rr < 2; ++rr) {
      const int seg = tid + rr * 256;
      const int row = seg >> 2, ks8 = (seg & 3) * 8;
      a_v[rr] = *(const uint4*)(Hall + (size_t)(m0 + row) * 512 + k0 + ks8);
    }
    float4 b_v[4];
#pragma unroll
    for (int rr = 0; rr < 4; ++rr) {
      const int idx = tid + rr * 256;
      const int n = idx >> 3, kg = (idx & 7) * 4;
      b_v[rr] = *(const float4*)(Wo + (size_t)(n0 + n) * 512 + k0 + kg);
    }
    __syncthreads();
#pragma unroll
    for (int rr = 0; rr < 2; ++rr) {
      const int seg = tid + rr * 256;
      *(uint4*)(Asub + seg * 8) = a_v[rr];
    }
#pragma unroll
    for (int rr = 0; rr < 4; ++rr) {
      const int idx = tid + rr * 256;
      const int n = idx >> 3, kg = (idx & 7) * 4;
      union { __hip_bfloat16 h[4]; uint2 u; } cv;
      cv.h[0] = __float2bfloat16(b_v[rr].x);
      cv.h[1] = __float2bfloat16(b_v[rr].y);
      cv.h[2] = __float2bfloat16(b_v[rr].z);
      cv.h[3] = __float2bfloat16(b_v[rr].w);
      *(uint2*)(Bsub + n * 32 + kg) = cv.u;
    }
    __syncthreads();
    bf16x8 af[4], bfr[4];
#pragma unroll
    for (int mi = 0; mi < 4; ++mi)
      af[mi] = *(const bf16x8*)(Asub + (wr * 64 + mi * 16 + (lane & 15)) * 32 + (lane >> 4) * 8);
#pragma unroll
    for (int ni = 0; ni < 4; ++ni)
      bfr[ni] = *(const bf16x8*)(Bsub + (wc * 64 + ni * 16 + (lane & 15)) * 32 + (lane >> 4) * 8);
#pragma unroll
    for (int mi = 0; mi < 4; ++mi)
#pragma unroll
      for (int ni = 0; ni < 4; ++ni)
        acc[mi][ni] = __builtin_amdgcn_mfma_f32_16x16x32_bf16(af[mi], bfr[ni], acc[mi][ni], 0, 0, 0);
  }

  float* Cs = pool;
  const int r4 = (lane >> 4) * 4, cc = lane & 15;
  const int rowp = tid >> 4, colg = tid & 15;
  float es[8] = {0.f, 0.f, 0.f, 0.f, 0.f, 0.f, 0.f, 0.f};
#pragma unroll
  for (int hf = 0; hf < 2; ++hf) {
    __syncthreads();
    if (wc == hf) {
#pragma unroll
      for (int ni = 0; ni < 4; ++ni) {
        const float bias = bo[n0 + hf * 64 + ni * 16 + cc];
#pragma unroll
        for (int mi = 0; mi < 4; ++mi)
#pragma unroll
          for (int i = 0; i < 4; ++i)
            Cs[(wr * 64 + mi * 16 + r4 + i) * 68 + ni * 16 + cc] = acc[mi][ni][i] + bias;
      }
    }
    __syncthreads();
#pragma unroll
    for (int pass = 0; pass < 8; ++pass) {
      const int row = pass * 16 + rowp;
      const float4 v = *(const float4*)(Cs + row * 68 + colg * 4);
      *(float4*)(out0 + (size_t)(m0 + row) * V_ + n0 + hf * 64 + colg * 4) = v;
      es[pass] += __expf(v.x) + __expf(v.y) + __expf(v.z) + __expf(v.w);
    }
  }
#pragma unroll
  for (int pass = 0; pass < 8; ++pass) {
    float e = es[pass];
#pragma unroll
    for (int d = 1; d < 16; d <<= 1) e += __shfl_xor(e, d);
    if (colg == 0)
      atomicAdd(&rowsum[(size_t)(m0 + pass * 16 + rowp) * 16], e);
  }
}

// ---------------- log_softmax apply: out -= log(rowsum[row]) ----------------

__global__ __launch_bounds__(256) void k_lsm_apply(float* __restrict__ out0,
    const float* __restrict__ rowsum) {
  const int row = blockIdx.x, tid = threadIdx.x;
  const float lse = __logf(rowsum[(size_t)row * 16]);
  float4* p = (float4*)(out0 + (size_t)row * V_);
  for (int i = tid; i < V_ / 4; i += 256) {
    float4 v = p[i];
    v.x -= lse; v.y -= lse; v.z -= lse; v.w -= lse;
    p[i] = v;
  }
}

// ---------------- host ----------------

extern "C" void kernel_launch(void* const* d_in, const int* in_sizes, int n_in,
                              void* d_out, int out_size, void* d_ws, size_t ws_size,
                              hipStream_t stream) {
  (void)in_sizes; (void)n_in; (void)out_size; (void)ws_size;
  const float* enc  = (const float*)d_in[0];
  const float* ehs  = (const float*)d_in[1];
  const int*   tgt  = (const int*)d_in[2];
  const float* emb  = (const float*)d_in[3];
  const float* Wq   = (const float*)d_in[4];
  const float* bq   = (const float*)d_in[5];
  const float* Wk   = (const float*)d_in[6];
  const float* bk   = (const float*)d_in[7];
  const float* Wv   = (const float*)d_in[8];
  const float* bv   = (const float*)d_in[9];
  const float* W_ih = (const float*)d_in[10];
  const float* W_hh = (const float*)d_in[11];
  const float* b_ih = (const float*)d_in[12];
  const float* b_hh = (const float*)d_in[13];
  const float* Wo   = (const float*)d_in[14];
  const float* bo   = (const float*)d_in[15];

  float* out0 = (float*)d_out;                          // log_probs [2048, V]
  float* out1 = out0 + (size_t)B_ * T_ * V_;            // h_final [B*H]
  float* out2 = out1 + (size_t)B_ * H_;                 // attentions [B*T, S]

  // out0 doubles as scratch; k_logits overwrites all of it afterwards.
  float* giemb    = out0;                 // [0, 3,145,728)
  float* partial  = out0 + 3145728;       // 64x32x512 -> [.., 4,194,304)
  float* gh_st    = out0 + 4194304;       // 64x32x1536 -> [.., 7,340,032)
  __hip_bfloat16* enc_bf   = (__hip_bfloat16*)(out0 + 7340032);   // 1M bf16
  __hip_bfloat16* emb_bf   = (__hip_bfloat16*)(out0 + 7864320);   // 1M bf16
  __hip_bfloat16* wihc_bf  = (__hip_bfloat16*)(out0 + 8388608);   // 0.75M bf16
  __hip_bfloat16* wq_bf    = (__hip_bfloat16*)(out0 + 8781824);   // 256K bf16
  __hip_bfloat16* whh_bf   = (__hip_bfloat16*)(out0 + 8912896);   // 0.75M bf16
  __hip_bfloat16* kproj_bf = (__hip_bfloat16*)(out0 + 9306112);   // 1M bf16
  __hip_bfloat16* encT_bf  = (__hip_bfloat16*)(out0 + 9830400);   // 3M bf16

  __hip_bfloat16* Hall = (__hip_bfloat16*)d_ws;                    // 2 MB
  int* flags = (int*)((char*)d_ws + (size_t)2 * 1024 * 1024);      // 512 ints
  float* rowsum = (float*)((char*)d_ws + (size_t)2 * 1024 * 1024 + 2048);  // 2048*16 f

  k_prep<<<6787, 256, 0, stream>>>(tgt, emb, enc, W_ih, Wq, W_hh,
                                   emb_bf, enc_bf, wihc_bf, wq_bf, whh_bf,
                                   flags, rowsum);

  // kproj_bf[2048,512] = enc @ Wk^T + bk   (bf16 out)
  k_gemm<true><<<dim3(4, 16), 256, 0, stream>>>(enc_bf, 512, Wk, 512, bk, kproj_bf, 512, 512);
  // giemb[2048,1536] = emb_all @ W_ih[:, :512]^T + b_ih   (f32 out)
  k_gemm<false><<<dim3(12, 16), 256, 0, stream>>>(emb_bf, 512, W_ih, 1024, b_ih, giemb, 1536, 512);
  // encT_bf[1536,2048] = W_ihc @ enc^T   (bf16 out)
  k_gemm<true><<<dim3(16, 12), 256, 0, stream>>>(wihc_bf, 512, enc, 512, nullptr, encT_bf, 2048, 512);

  k_recur<<<256, 256, 0, stream>>>(wq_bf, whh_bf, bq, kproj_bf, Wv, bv, encT_bf,
                                   giemb, b_hh, ehs, partial, gh_st, flags,
                                   out2, Hall, out1);

  k_logits<<<4000, 256, 0, stream>>>(Hall, Wo, bo, out0, rowsum);
  k_lsm_apply<<<(B_ * T_), 256, 0, stream>>>(out0, rowsum);
}

// Round 16
// 1233.480 us; speedup vs baseline: 4.9679x; 4.9679x over previous
//
#include <hip/hip_runtime.h>
#include <hip/hip_bf16.h>

#define B_ 32
#define S_ 64
#define H_ 512
#define V_ 32000
#define T_ 64

typedef __bf16 bf16x8 __attribute__((ext_vector_type(8)));
typedef float f32x4 __attribute__((ext_vector_type(4)));

__device__ __forceinline__ float fast_tanh(float x) {
  float e = __expf(2.0f * x);
  return 1.0f - 2.0f / (e + 1.0f);
}
__device__ __forceinline__ float fast_sigmoid(float x) {
  return 1.0f / (1.0f + __expf(-x));
}
__device__ __forceinline__ int ld_agent(const int* p) {
  return __hip_atomic_load(p, __ATOMIC_RELAXED, __HIP_MEMORY_SCOPE_AGENT);
}
__device__ __forceinline__ void st_agent_f(float* p, float v) {
  __hip_atomic_store(p, v, __ATOMIC_RELAXED, __HIP_MEMORY_SCOPE_AGENT);
}
__device__ __forceinline__ void st_agent_i(int* p, int v) {
  __hip_atomic_store(p, v, __ATOMIC_RELAXED, __HIP_MEMORY_SCOPE_AGENT);
}

// ---------------- merged prep kernel (block-ranged) ----------------
// [0,2048): emb gather->bf16 ; [2048,3072): enc cvt ; [3072,4608): wihc cvt ;
// [4608,6656): wq/whh cvt ; [6656,6852): init h_st0/flags/rowsum.

__global__ __launch_bounds__(256) void k_prep(
    const int* __restrict__ tgt, const float* __restrict__ emb,
    const float* __restrict__ enc, const float* __restrict__ W_ih,
    const float* __restrict__ Wq, const float* __restrict__ W_hh,
    const float* __restrict__ ehs,
    __hip_bfloat16* __restrict__ emb_bf, __hip_bfloat16* __restrict__ enc_bf,
    __hip_bfloat16* __restrict__ wihc_bf, __hip_bfloat16* __restrict__ wq_bf,
    __hip_bfloat16* __restrict__ whh_bf,
    float* __restrict__ h_st0, int* __restrict__ flags,
    float* __restrict__ rowsum) {
  const int bid = blockIdx.x, tid = threadIdx.x;
  if (bid < 2048) {
    const int t = bid >> 5, b = bid & 31;
    const int tok = (t == 0) ? 0 : tgt[b * T_ + t - 1];
    const float* src = emb + (size_t)tok * H_;
    __hip_bfloat16* dst = emb_bf + (size_t)bid * H_;
    for (int jj = tid; jj < H_; jj += 256) dst[jj] = __float2bfloat16(src[jj]);
  } else if (bid < 3072) {
    const int i = (bid - 2048) * 256 + tid;          // < 262144 float4s
    const float4 v = ((const float4*)enc)[i];
    union { __hip_bfloat16 h[4]; uint2 u; } cv;
    cv.h[0] = __float2bfloat16(v.x); cv.h[1] = __float2bfloat16(v.y);
    cv.h[2] = __float2bfloat16(v.z); cv.h[3] = __float2bfloat16(v.w);
    *(uint2*)(enc_bf + (size_t)i * 4) = cv.u;
  } else if (bid < 4608) {
    if (tid < 128) {
      const int row = bid - 3072;                    // 0..1535
      const int c4 = tid * 4;
      const float4 v = *(const float4*)(W_ih + (size_t)row * 1024 + 512 + c4);
      union { __hip_bfloat16 h[4]; uint2 u; } cv;
      cv.h[0] = __float2bfloat16(v.x); cv.h[1] = __float2bfloat16(v.y);
      cv.h[2] = __float2bfloat16(v.z); cv.h[3] = __float2bfloat16(v.w);
      *(uint2*)(wihc_bf + (size_t)row * 512 + c4) = cv.u;
    }
  } else if (bid < 6656) {
    const int row = bid - 4608;                      // 0..2047
    const int c2 = tid * 2;
    const float* src = (row < 512) ? (Wq + (size_t)row * 512)
                                   : (W_hh + (size_t)(row - 512) * 512);
    __hip_bfloat16* dst = (row < 512) ? (wq_bf + (size_t)row * 512)
                                      : (whh_bf + (size_t)(row - 512) * 512);
    const float2 v = *(const float2*)(src + c2);
    union { __hip_bfloat16 h[2]; unsigned u; } cv;
    cv.h[0] = __float2bfloat16(v.x); cv.h[1] = __float2bfloat16(v.y);
    *(unsigned*)(dst + c2) = cv.u;
  } else {
    const int i = (bid - 6656) * 256 + tid;
    if (i < 16384) h_st0[i] = ehs[i];
    else if (i < 17408)
      __hip_atomic_store(&flags[i - 16384], 0, __ATOMIC_RELAXED, __HIP_MEMORY_SCOPE_AGENT);
    else if (i < 50176) rowsum[i - 17408] = 0.f;
  }
}

// ---------------- bf16-MFMA GEMM: C[M,N] = A[M,K] @ B[N,K]^T (+bias) ----------------

template <bool BF16OUT>
__global__ __launch_bounds__(256) void k_gemm(
    const __hip_bfloat16* __restrict__ A, int lda,
    const float* __restrict__ B, int ldb,
    const float* __restrict__ bias,
    void* __restrict__ Cv, int ldc, int K) {
  __shared__ float pool[128 * 68];
  __hip_bfloat16* Asub = (__hip_bfloat16*)pool;
  __hip_bfloat16* Bsub = (__hip_bfloat16*)(pool + 2048);
  const int tid = threadIdx.x;
  const int lane = tid & 63, wave = tid >> 6;
  const int wr = wave >> 1, wc = wave & 1;
  const int n0 = blockIdx.x * 128, m0 = blockIdx.y * 128;
  f32x4 acc[4][4];
#pragma unroll
  for (int i = 0; i < 4; ++i)
#pragma unroll
    for (int jj = 0; jj < 4; ++jj) acc[i][jj] = (f32x4){0.f, 0.f, 0.f, 0.f};

  for (int k0 = 0; k0 < K; k0 += 32) {
    uint4 a_v[2];
#pragma unroll
    for (int rr = 0; rr < 2; ++rr) {
      const int seg = tid + rr * 256;
      const int row = seg >> 2, ks8 = (seg & 3) * 8;
      a_v[rr] = *(const uint4*)(A + (size_t)(m0 + row) * lda + k0 + ks8);
    }
    float4 b_v[4];
#pragma unroll
    for (int rr = 0; rr < 4; ++rr) {
      const int idx = tid + rr * 256;
      const int n = idx >> 3, kg = (idx & 7) * 4;
      b_v[rr] = *(const float4*)(B + (size_t)(n0 + n) * ldb + k0 + kg);
    }
    __syncthreads();
#pragma unroll
    for (int rr = 0; rr < 2; ++rr) {
      const int seg = tid + rr * 256;
      *(uint4*)(Asub + seg * 8) = a_v[rr];
    }
#pragma unroll
    for (int rr = 0; rr < 4; ++rr) {
      const int idx = tid + rr * 256;
      const int n = idx >> 3, kg = (idx & 7) * 4;
      union { __hip_bfloat16 h[4]; uint2 u; } cv;
      cv.h[0] = __float2bfloat16(b_v[rr].x);
      cv.h[1] = __float2bfloat16(b_v[rr].y);
      cv.h[2] = __float2bfloat16(b_v[rr].z);
      cv.h[3] = __float2bfloat16(b_v[rr].w);
      *(uint2*)(Bsub + n * 32 + kg) = cv.u;
    }
    __syncthreads();
    bf16x8 af[4], bfr[4];
#pragma unroll
    for (int mi = 0; mi < 4; ++mi)
      af[mi] = *(const bf16x8*)(Asub + (wr * 64 + mi * 16 + (lane & 15)) * 32 + (lane >> 4) * 8);
#pragma unroll
    for (int ni = 0; ni < 4; ++ni)
      bfr[ni] = *(const bf16x8*)(Bsub + (wc * 64 + ni * 16 + (lane & 15)) * 32 + (lane >> 4) * 8);
#pragma unroll
    for (int mi = 0; mi < 4; ++mi)
#pragma unroll
      for (int ni = 0; ni < 4; ++ni)
        acc[mi][ni] = __builtin_amdgcn_mfma_f32_16x16x32_bf16(af[mi], bfr[ni], acc[mi][ni], 0, 0, 0);
  }

  float* Cs = pool;
  const int r4 = (lane >> 4) * 4, cc = lane & 15;
#pragma unroll
  for (int hf = 0; hf < 2; ++hf) {
    __syncthreads();
    if (wc == hf) {
#pragma unroll
      for (int ni = 0; ni < 4; ++ni) {
        const float bb = bias ? bias[n0 + hf * 64 + ni * 16 + cc] : 0.f;
#pragma unroll
        for (int mi = 0; mi < 4; ++mi)
#pragma unroll
          for (int i = 0; i < 4; ++i)
            Cs[(wr * 64 + mi * 16 + r4 + i) * 68 + ni * 16 + cc] = acc[mi][ni][i] + bb;
      }
    }
    __syncthreads();
    const int rowp = tid >> 4, colg = tid & 15;
#pragma unroll
    for (int pass = 0; pass < 8; ++pass) {
      const int row = pass * 16 + rowp;
      const float4 v = *(const float4*)(Cs + row * 68 + colg * 4);
      if constexpr (BF16OUT) {
        union { __hip_bfloat16 h[4]; uint2 u; } cv;
        cv.h[0] = __float2bfloat16(v.x); cv.h[1] = __float2bfloat16(v.y);
        cv.h[2] = __float2bfloat16(v.z); cv.h[3] = __float2bfloat16(v.w);
        *(uint2*)((__hip_bfloat16*)Cv + (size_t)(m0 + row) * ldc + n0 + hf * 64 + colg * 4) = cv.u;
      } else {
        *(float4*)((float*)Cv + (size_t)(m0 + row) * ldc + n0 + hf * 64 + colg * 4) = v;
      }
    }
  }
}

// ---------------- recurrence: r12 VERBATIM (measured 819 us, VGPR 100) ----------------
// 32 same-XCD clusters x 8 blocks: b = 4*(bid&7)+((bid>>3)&3), j = bid>>5.
// Two rendezvous/step; agent write-through payloads + vmcnt(0) + monotone
// 1-line flags + per-step rotating buffers (cold-miss reads).

__global__ __launch_bounds__(256) void k_recur(
    const __hip_bfloat16* __restrict__ wq_bf, const __hip_bfloat16* __restrict__ whh_bf,
    const float* __restrict__ bq,
    const __hip_bfloat16* __restrict__ kproj_bf,
    const float* __restrict__ Wv, const float* __restrict__ bv,
    const __hip_bfloat16* __restrict__ encT_bf, const float* __restrict__ giemb,
    const float* __restrict__ b_hh,
    float* h_st, float* partial_st, int* flags,
    float* __restrict__ attn_out, __hip_bfloat16* __restrict__ Hall,
    float* __restrict__ hfin) {
  const int tid = threadIdx.x;
  const int bid = blockIdx.x;
  const int b = 4 * (bid & 7) + ((bid >> 3) & 3);   // cluster (batch)
  const int j = bid >> 5;                           // slice
  int* h_flags  = flags;                // [b*16 + j]
  int* st_flags = flags + 512;          // [b*16 + j]

  const int rowg = tid >> 3, lane8 = tid & 7;
  const int s_idx = tid >> 2, q4 = tid & 3;
  f32x4 wvr[4];
#pragma unroll
  for (int i = 0; i < 4; ++i)
    wvr[i] = *(const f32x4*)(Wv + j * 64 + q4 * 16 + i * 4);
  float bq2[2];
#pragma unroll
  for (int i = 0; i < 2; ++i) bq2[i] = bq[j * 64 + i * 32 + rowg];
  const float bv0 = bv[0];

  __shared__ float h_s[8 * 68];
  __shared__ float q_s[64];
  __shared__ float gh_s[192];
  __shared__ float ps_s[512];
  __shared__ float w_s[64];
  __shared__ float gic_s[192];

  for (int t = 0; t < T_; ++t) {
    // ---- wait h_st[t][b] published by all 8 slices (1-line poll) ----
    if (tid < 8) {
      while (ld_agent(&h_flags[b * 16 + tid]) < t) __builtin_amdgcn_s_sleep(1);
    }
    __syncthreads();
    asm volatile("" ::: "memory");

    // ---- read h -> padded LDS ----
    const float* h_t = h_st + (size_t)t * (B_ * H_) + b * H_;
    if (tid < 128) {
      const float4 v = *(const float4*)(h_t + tid * 4);
      const int g = (tid * 4) >> 6, off = (tid * 4) & 63;
      *(float4*)(h_s + g * 68 + off) = v;
    }
    __syncthreads();

    f32x4 hf4[16];
#pragma unroll
    for (int i = 0; i < 16; ++i)
      hf4[i] = *(const f32x4*)(h_s + lane8 * 68 + i * 4);

    // streaming bf16 GEMV: dot(wrow[lane8*64 .. +64), h-chunk), reduce over lane8
    auto dotw = [&](const __hip_bfloat16* wrow) -> float {
      const uint4* w8 = (const uint4*)wrow;
      float p = 0.f;
#pragma unroll
      for (int i = 0; i < 8; ++i) {
        const uint4 w = w8[lane8 * 8 + i];
        const f32x4 ha = hf4[2 * i], hb = hf4[2 * i + 1];
        p += __uint_as_float(w.x << 16) * ha[0] + __uint_as_float(w.x & 0xffff0000u) * ha[1];
        p += __uint_as_float(w.y << 16) * ha[2] + __uint_as_float(w.y & 0xffff0000u) * ha[3];
        p += __uint_as_float(w.z << 16) * hb[0] + __uint_as_float(w.z & 0xffff0000u) * hb[1];
        p += __uint_as_float(w.w << 16) * hb[2] + __uint_as_float(w.w & 0xffff0000u) * hb[3];
      }
      p += __shfl_xor(p, 1); p += __shfl_xor(p, 2); p += __shfl_xor(p, 4);
      return p;
    };

    // ---- q slice: rows j*64 .. +64 of Wq ----
#pragma unroll
    for (int i = 0; i < 2; ++i) {
      const float p = dotw(wq_bf + (size_t)(j * 64 + i * 32 + rowg) * 512);
      if (lane8 == 0) q_s[i * 32 + rowg] = p + bq2[i];
    }
    __syncthreads();

    // ---- partial scores over this slice's 64 h-dims (bf16 kproj) ----
    {
      const uint4* kp = (const uint4*)(kproj_bf + ((size_t)(b * S_ + s_idx)) * H_ + j * 64 + q4 * 16);
      const float4* qp = (const float4*)(q_s + q4 * 16);
      float sc = 0.f;
#pragma unroll
      for (int i = 0; i < 2; ++i) {
        const uint4 k = kp[i];
        const float4 qa = qp[2 * i], qb = qp[2 * i + 1];
        const f32x4 va = wvr[2 * i], vb = wvr[2 * i + 1];
        sc += va[0] * fast_tanh(qa.x + __uint_as_float(k.x << 16));
        sc += va[1] * fast_tanh(qa.y + __uint_as_float(k.x & 0xffff0000u));
        sc += va[2] * fast_tanh(qa.z + __uint_as_float(k.y << 16));
        sc += va[3] * fast_tanh(qa.w + __uint_as_float(k.y & 0xffff0000u));
        sc += vb[0] * fast_tanh(qb.x + __uint_as_float(k.z << 16));
        sc += vb[1] * fast_tanh(qb.y + __uint_as_float(k.z & 0xffff0000u));
        sc += vb[2] * fast_tanh(qb.z + __uint_as_float(k.w << 16));
        sc += vb[3] * fast_tanh(qb.w + __uint_as_float(k.w & 0xffff0000u));
      }
      sc += __shfl_xor(sc, 1); sc += __shfl_xor(sc, 2);
      if (q4 == 0)
        st_agent_f(&partial_st[(((size_t)t * B_ + b) * 8 + j) * 64 + s_idx], sc);
    }
    asm volatile("s_waitcnt vmcnt(0)" ::: "memory");
    __syncthreads();
    if (tid == 0)
      st_agent_i(&st_flags[b * 16 + j], t + 1);

    // ---- gh rows (192), overlaps partial flight ----
#pragma unroll
    for (int i = 0; i < 6; ++i) {
      const int row = (i >> 1) * 512 + j * 64 + (i & 1) * 32 + rowg;
      const float p = dotw(whh_bf + (size_t)row * 512);
      if (lane8 == 0) gh_s[i * 32 + rowg] = p;
    }

    // ---- wait all 8 partials, read once ----
    if (tid < 8) {
      while (ld_agent(&st_flags[b * 16 + tid]) < t + 1) __builtin_amdgcn_s_sleep(1);
    }
    __syncthreads();
    asm volatile("" ::: "memory");
    if (tid < 128) {
      const float4 v = *(const float4*)(partial_st + ((size_t)t * B_ + b) * 512 + tid * 4);
      *(float4*)(ps_s + tid * 4) = v;
    }
    __syncthreads();

    // ---- softmax (redundant per block, bitwise identical) ----
    if (tid < 64) {
      float sc = bv0;
#pragma unroll
      for (int jj = 0; jj < 8; ++jj) sc += ps_s[jj * 64 + tid];
      float m = sc;
#pragma unroll
      for (int d = 32; d > 0; d >>= 1) m = fmaxf(m, __shfl_xor(m, d));
      const float e = __expf(sc - m);
      float sum = e;
#pragma unroll
      for (int d = 32; d > 0; d >>= 1) sum += __shfl_xor(sum, d);
      const float w = e / sum;
      w_s[tid] = w;
      if (j == (b & 7)) attn_out[((size_t)b * T_ + t) * S_ + tid] = w;
    }
    __syncthreads();

    // ---- gic slice j (bf16 encT) ----
    if (tid < 192) {
      const int g = tid >> 6, dd = tid & 63;
      const int grow = g * H_ + j * 64 + dd;
      const uint4* ep = (const uint4*)(encT_bf + (size_t)grow * 2048 + b * 64);
      const float4* wp4 = (const float4*)w_s;
      float a = 0.f;
#pragma unroll
      for (int i = 0; i < 8; ++i) {
        const uint4 e4 = ep[i];
        const float4 w0 = wp4[2 * i], w1 = wp4[2 * i + 1];
        a += __uint_as_float(e4.x << 16) * w0.x + __uint_as_float(e4.x & 0xffff0000u) * w0.y;
        a += __uint_as_float(e4.y << 16) * w0.z + __uint_as_float(e4.y & 0xffff0000u) * w0.w;
        a += __uint_as_float(e4.z << 16) * w1.x + __uint_as_float(e4.z & 0xffff0000u) * w1.y;
        a += __uint_as_float(e4.w << 16) * w1.z + __uint_as_float(e4.w & 0xffff0000u) * w1.w;
      }
      gic_s[tid] = a;
    }
    __syncthreads();

    // ---- gates for h-dims [j*64,(j+1)*64) ----
    if (tid < 64) {
      const int hh = j * 64 + tid;
      const size_t grow = ((size_t)t * B_ + b) * 1536;
      const float ir  = giemb[grow + hh]        + gic_s[tid];
      const float iz  = giemb[grow + 512 + hh]  + gic_s[64 + tid];
      const float in_ = giemb[grow + 1024 + hh] + gic_s[128 + tid];
      const float hr  = gh_s[tid]        + b_hh[hh];
      const float hz  = gh_s[64 + tid]   + b_hh[512 + hh];
      const float hn  = gh_s[128 + tid]  + b_hh[1024 + hh];
      const float rg = fast_sigmoid(ir + hr);
      const float zg = fast_sigmoid(iz + hz);
      const float ng = fast_tanh(in_ + rg * hn);
      const float ho = h_s[j * 68 + tid];
      const float hv = (1.f - zg) * ng + zg * ho;
      st_agent_f(&h_st[(size_t)(t + 1) * (B_ * H_) + b * H_ + hh], hv);
      Hall[((size_t)b * T_ + t) * H_ + hh] = __float2bfloat16(hv);
      if (t == T_ - 1) hfin[b * H_ + hh] = hv;
    }
    asm volatile("s_waitcnt vmcnt(0)" ::: "memory");
    __syncthreads();
    if (tid == 0)
      st_agent_i(&h_flags[b * 16 + j], t + 1);
  }
}

// ---------------- logits GEMM + fused sumexp (XCD-chunked n-tiles) ----------------
// |h|<=1 -> |logit| <~ 10 -> no-max sumexp fp32-safe. rowsum padded: 1 line/row.

__global__ __launch_bounds__(256) void k_logits(
    const __hip_bfloat16* __restrict__ Hall, const float* __restrict__ Wo,
    const float* __restrict__ bo, float* __restrict__ out0,
    float* __restrict__ rowsum) {
  __shared__ float pool[128 * 68];
  __hip_bfloat16* Asub = (__hip_bfloat16*)pool;
  __hip_bfloat16* Bsub = (__hip_bfloat16*)(pool + 2048);
  const int tid = threadIdx.x;
  const int lane = tid & 63, wave = tid >> 6;
  const int wr = wave >> 1, wc = wave & 1;
  const int flat = blockIdx.x;                  // 0..3999
  const int nf = (flat & 7) * 500 + (flat >> 3);
  const int m0 = (nf & 15) * 128, n0 = (nf >> 4) * 128;
  f32x4 acc[4][4];
#pragma unroll
  for (int i = 0; i < 4; ++i)
#pragma unroll
    for (int jj = 0; jj < 4; ++jj) acc[i][jj] = (f32x4){0.f, 0.f, 0.f, 0.f};

  for (int k0 = 0; k0 < 512; k0 += 32) {
    uint4 a_v[2];
#pragma unroll
    for (int rr = 0; rr < 2; ++rr) {
      const int seg = tid + rr * 256;
      const int row = seg >> 2, ks8 = (seg & 3) * 8;
      a_v[rr] = *(const uint4*)(Hall + (size_t)(m0 + row) * 512 + k0 + ks8);
    }
    float4 b_v[4];
#pragma unroll
    for (int rr = 0; rr < 4; ++rr) {
      const int idx = tid + rr * 256;
      const int n = idx >> 3, kg = (idx & 7) * 4;
      b_v[rr] = *(const float4*)(Wo + (size_t)(n0 + n) * 512 + k0 + kg);
    }
    __syncthreads();
#pragma unroll
    for (int rr = 0; rr < 2; ++rr) {
      const int seg = tid + rr * 256;
      *(uint4*)(Asub + seg * 8) = a_v[rr];
    }
#pragma unroll
    for (int rr = 0; rr < 4; ++rr) {
      const int idx = tid + rr * 256;
      const int n = idx >> 3, kg = (idx & 7) * 4;
      union { __hip_bfloat16 h[4]; uint2 u; } cv;
      cv.h[0] = __float2bfloat16(b_v[rr].x);
      cv.h[1] = __float2bfloat16(b_v[rr].y);
      cv.h[2] = __float2bfloat16(b_v[rr].z);
      cv.h[3] = __float2bfloat16(b_v[rr].w);
      *(uint2*)(Bsub + n * 32 + kg) = cv.u;
    }
    __syncthreads();
    bf16x8 af[4], bfr[4];
#pragma unroll
    for (int mi = 0; mi < 4; ++mi)
      af[mi] = *(const bf16x8*)(Asub + (wr * 64 + mi * 16 + (lane & 15)) * 32 + (lane >> 4) * 8);
#pragma unroll
    for (int ni = 0; ni < 4; ++ni)
      bfr[ni] = *(const bf16x8*)(Bsub + (wc * 64 + ni * 16 + (lane & 15)) * 32 + (lane >> 4) * 8);
#pragma unroll
    for (int mi = 0; mi < 4; ++mi)
#pragma unroll
      for (int ni = 0; ni < 4; ++ni)
        acc[mi][ni] = __builtin_amdgcn_mfma_f32_16x16x32_bf16(af[mi], bfr[ni], acc[mi][ni], 0, 0, 0);
  }

  float* Cs = pool;
  const int r4 = (lane >> 4) * 4, cc = lane & 15;
  const int rowp = tid >> 4, colg = tid & 15;
  float es[8] = {0.f, 0.f, 0.f, 0.f, 0.f, 0.f, 0.f, 0.f};
#pragma unroll
  for (int hf = 0; hf < 2; ++hf) {
    __syncthreads();
    if (wc == hf) {
#pragma unroll
      for (int ni = 0; ni < 4; ++ni) {
        const float bias = bo[n0 + hf * 64 + ni * 16 + cc];
#pragma unroll
        for (int mi = 0; mi < 4; ++mi)
#pragma unroll
          for (int i = 0; i < 4; ++i)
            Cs[(wr * 64 + mi * 16 + r4 + i) * 68 + ni * 16 + cc] = acc[mi][ni][i] + bias;
      }
    }
    __syncthreads();
#pragma unroll
    for (int pass = 0; pass < 8; ++pass) {
      const int row = pass * 16 + rowp;
      const float4 v = *(const float4*)(Cs + row * 68 + colg * 4);
      *(float4*)(out0 + (size_t)(m0 + row) * V_ + n0 + hf * 64 + colg * 4) = v;
      es[pass] += __expf(v.x) + __expf(v.y) + __expf(v.z) + __expf(v.w);
    }
  }
#pragma unroll
  for (int pass = 0; pass < 8; ++pass) {
    float e = es[pass];
#pragma unroll
    for (int d = 1; d < 16; d <<= 1) e += __shfl_xor(e, d);
    if (colg == 0)
      atomicAdd(&rowsum[(size_t)(m0 + pass * 16 + rowp) * 16], e);
  }
}

// ---------------- log_softmax apply: out -= log(rowsum[row]) ----------------

__global__ __launch_bounds__(256) void k_lsm_apply(float* __restrict__ out0,
    const float* __restrict__ rowsum) {
  const int row = blockIdx.x, tid = threadIdx.x;
  const float lse = __logf(rowsum[(size_t)row * 16]);
  float4* p = (float4*)(out0 + (size_t)row * V_);
  for (int i = tid; i < V_ / 4; i += 256) {
    float4 v = p[i];
    v.x -= lse; v.y -= lse; v.z -= lse; v.w -= lse;
    p[i] = v;
  }
}

// ---------------- host ----------------

extern "C" void kernel_launch(void* const* d_in, const int* in_sizes, int n_in,
                              void* d_out, int out_size, void* d_ws, size_t ws_size,
                              hipStream_t stream) {
  (void)in_sizes; (void)n_in; (void)out_size; (void)ws_size;
  const float* enc  = (const float*)d_in[0];
  const float* ehs  = (const float*)d_in[1];
  const int*   tgt  = (const int*)d_in[2];
  const float* emb  = (const float*)d_in[3];
  const float* Wq   = (const float*)d_in[4];
  const float* bq   = (const float*)d_in[5];
  const float* Wk   = (const float*)d_in[6];
  const float* bk   = (const float*)d_in[7];
  const float* Wv   = (const float*)d_in[8];
  const float* bv   = (const float*)d_in[9];
  const float* W_ih = (const float*)d_in[10];
  const float* W_hh = (const float*)d_in[11];
  const float* b_ih = (const float*)d_in[12];
  const float* b_hh = (const float*)d_in[13];
  const float* Wo   = (const float*)d_in[14];
  const float* bo   = (const float*)d_in[15];

  float* out0 = (float*)d_out;                          // log_probs [2048, V]
  float* out1 = out0 + (size_t)B_ * T_ * V_;            // h_final [B*H]
  float* out2 = out1 + (size_t)B_ * H_;                 // attentions [B*T, S]

  // out0 doubles as scratch; k_logits overwrites all of it afterwards.
  float* giemb    = out0;                 // [0, 3,145,728)
  float* h_st     = out0 + 3145728;       // 65 x 16384 -> [.., 4,210,688)
  float* partial  = out0 + 4210688;       // 64x32x512 -> [.., 5,259,264)
  __hip_bfloat16* enc_bf   = (__hip_bfloat16*)(out0 + 5259264);   // 1M bf16
  __hip_bfloat16* emb_bf   = (__hip_bfloat16*)(out0 + 5783552);   // 1M bf16
  __hip_bfloat16* wihc_bf  = (__hip_bfloat16*)(out0 + 6307840);   // 0.75M bf16
  __hip_bfloat16* wq_bf    = (__hip_bfloat16*)(out0 + 6701056);   // 256K bf16
  __hip_bfloat16* whh_bf   = (__hip_bfloat16*)(out0 + 6832128);   // 0.75M bf16
  __hip_bfloat16* kproj_bf = (__hip_bfloat16*)(out0 + 7225344);   // 1M bf16
  __hip_bfloat16* encT_bf  = (__hip_bfloat16*)(out0 + 7749632);   // 3M bf16

  __hip_bfloat16* Hall = (__hip_bfloat16*)d_ws;                    // 2 MB
  int* flags = (int*)((char*)d_ws + (size_t)2 * 1024 * 1024);      // 1024 ints
  float* rowsum = (float*)((char*)d_ws + (size_t)2 * 1024 * 1024 + 4096);  // 2048*16 f

  k_prep<<<6852, 256, 0, stream>>>(tgt, emb, enc, W_ih, Wq, W_hh, ehs,
                                   emb_bf, enc_bf, wihc_bf, wq_bf, whh_bf,
                                   h_st, flags, rowsum);

  // kproj_bf[2048,512] = enc @ Wk^T + bk   (bf16 out)
  k_gemm<true><<<dim3(4, 16), 256, 0, stream>>>(enc_bf, 512, Wk, 512, bk, kproj_bf, 512, 512);
  // giemb[2048,1536] = emb_all @ W_ih[:, :512]^T + b_ih   (f32 out)
  k_gemm<false><<<dim3(12, 16), 256, 0, stream>>>(emb_bf, 512, W_ih, 1024, b_ih, giemb, 1536, 512);
  // encT_bf[1536,2048] = W_ihc @ enc^T   (bf16 out)
  k_gemm<true><<<dim3(16, 12), 256, 0, stream>>>(wihc_bf, 512, enc, 512, nullptr, encT_bf, 2048, 512);

  k_recur<<<256, 256, 0, stream>>>(wq_bf, whh_bf, bq, kproj_bf, Wv, bv, encT_bf,
                                   giemb, b_hh, h_st, partial, flags,
                                   out2, Hall, out1);

  k_logits<<<4000, 256, 0, stream>>>(Hall, Wo, bo, out0, rowsum);
  k_lsm_apply<<<(B_ * T_), 256, 0, stream>>>(out0, rowsum);
}